// Round 1
// baseline (4120.835 us; speedup 1.0000x reference)
//
#include <hip/hip_runtime.h>
#include <hip/hip_bf16.h>
#include <cstddef>

// NLBasicBlock fused pipeline, fp32 baseline (round 1).
// x:[2,64,80,80] -> conv3x3(reflect)+prelu -> nonlocal (softmax over dim=1!)
// -> +residuals -> conv3x3(reflect)+prelu.
// Softmax trick: normalization axis (i) differs from reduction axis (j), so
// precompute rS_j = 1/sum_i exp(f_ij - 20) (fixed shift, no max pass), then
// y = (exp(f-20) * rS_j) @ g  -- a plain GEMM-exp-GEMM, f never materialized.

constexpr int kB = 2, kC = 64, kH = 80, kW = 80, kN = kH * kW;

__device__ __forceinline__ int refl(int i, int n) {
  return i < 0 ? -i : (i >= n ? 2 * n - 2 - i : i);
}

#define FMA64(wrp, xv)                                   \
  {                                                      \
    _Pragma("unroll") for (int o_ = 0; o_ < 64; ++o_)    \
        acc[o_] += (wrp)[o_] * (xv);                     \
  }

// ---- weight transposes: w3x3 [o][ci][9] -> [ci][9][o]; w1x1 [o][c] -> [c][o]
__global__ void k_prep(const float* __restrict__ w1, const float* __restrict__ w2,
                       const float* __restrict__ wg, const float* __restrict__ wth,
                       const float* __restrict__ wph, const float* __restrict__ wWm,
                       float* __restrict__ w1t, float* __restrict__ w2t,
                       float* __restrict__ wtht, float* __restrict__ wpht,
                       float* __restrict__ wgt, float* __restrict__ wWt) {
  int idx = blockIdx.x * 256 + threadIdx.x;
  if (idx < kC * kC * 9) {
    int o = idx / (kC * 9);
    int r = idx % (kC * 9);
    int ci = r / 9, tap = r % 9;
    int d = (ci * 9 + tap) * kC + o;
    w1t[d] = w1[idx];
    w2t[d] = w2[idx];
  }
  if (idx < kC * kC) {
    int o = idx / kC, c = idx % kC;
    int d = c * kC + o;
    wtht[d] = wth[idx];
    wpht[d] = wph[idx];
    wgt[d] = wg[idx];
    wWt[d] = wWm[idx];
  }
}

// ---- 3x3 reflect conv. MODE 0: write raw conv -> dst_raw [B][C][N] and
// prelu, pixel-major -> dst_pt [B][N][C]. MODE 1: write prelu -> dst_raw only.
template <int MODE>
__global__ __launch_bounds__(256) void k_conv3x3(
    const float* __restrict__ src,   // [B][C][H][W]
    const float* __restrict__ wt,    // [ci][9][64o]
    const float* __restrict__ alphap,
    float* __restrict__ dst_raw,
    float* __restrict__ dst_pt) {
  const int tile = blockIdx.x;  // 25 tiles of 16x16
  const int cog = blockIdx.y;   // 4 groups of 16 output channels
  const int b = blockIdx.z;
  const int ty0 = (tile / 5) * 16, tx0 = (tile % 5) * 16;
  const int tid = threadIdx.x;
  const int ty = tid / 16, tx = tid % 16;
  const float alpha = alphap[0];

  __shared__ float lds[32 * 18 * 18];  // 41.5 KB, one ci-chunk halo tile
  float acc[16];
#pragma unroll
  for (int o = 0; o < 16; ++o) acc[o] = 0.f;

  for (int chunk = 0; chunk < 2; ++chunk) {
    const int ci0 = chunk * 32;
    __syncthreads();
    for (int idx = tid; idx < 32 * 324; idx += 256) {
      int cc = idx / 324;
      int r = idx % 324;
      int hh = r / 18, ww = r % 18;
      int gh = refl(ty0 - 1 + hh, kH);
      int gw = refl(tx0 - 1 + ww, kW);
      lds[idx] = src[(((size_t)b * kC + ci0 + cc) * kH + gh) * kW + gw];
    }
    __syncthreads();
    for (int cc = 0; cc < 32; ++cc) {
#pragma unroll
      for (int tap = 0; tap < 9; ++tap) {
        const int dh = tap / 3, dw = tap % 3;
        const float xv = lds[cc * 324 + (ty + dh) * 18 + (tx + dw)];
        const float* wr = wt + ((size_t)(ci0 + cc) * 9 + tap) * kC + cog * 16;
#pragma unroll
        for (int o = 0; o < 16; ++o) acc[o] += wr[o] * xv;
      }
    }
  }

  const int n = (ty0 + ty) * kW + (tx0 + tx);
#pragma unroll
  for (int o = 0; o < 16; ++o) {
    const int co = cog * 16 + o;
    const float v = acc[o];
    const float p = v >= 0.f ? v : alpha * v;
    if (MODE == 0) {
      dst_raw[((size_t)b * kC + co) * kN + n] = v;
      dst_pt[((size_t)b * kN + n) * kC + co] = p;
    } else {
      dst_raw[((size_t)b * kC + co) * kN + n] = p;
    }
  }
}

// ---- three 1x1 convs: out[m][b][n][o] = sum_c wt3[m][c][o] * pT[b][n][c]
__global__ __launch_bounds__(64) void k_pw3(const float* __restrict__ pT,
                                            const float* __restrict__ wt3,
                                            float* __restrict__ outb) {
  const int m = blockIdx.z, b = blockIdx.y;
  const int n = blockIdx.x * 64 + threadIdx.x;
  const float* wt = wt3 + (size_t)m * kC * kC;
  const float4* p4 = (const float4*)(pT + ((size_t)b * kN + n) * kC);
  float acc[64];
#pragma unroll
  for (int o = 0; o < 64; ++o) acc[o] = 0.f;
#pragma unroll
  for (int cq = 0; cq < 16; ++cq) {
    const float4 t = p4[cq];
    const float* wr = wt + cq * 4 * 64;
    FMA64(wr, t.x);
    FMA64(wr + 64, t.y);
    FMA64(wr + 128, t.z);
    FMA64(wr + 192, t.w);
  }
  float4* d4 = (float4*)(outb + (((size_t)m * kB + b) * kN + n) * kC);
#pragma unroll
  for (int q = 0; q < 16; ++q)
    d4[q] = make_float4(acc[q * 4], acc[q * 4 + 1], acc[q * 4 + 2], acc[q * 4 + 3]);
}

// ---- column stats: rs[b][j] = 1 / sum_i exp(theta_i . phi_j - 20)
__global__ __launch_bounds__(256) void k_colstat(const float* __restrict__ th,
                                                 const float* __restrict__ ph,
                                                 float* __restrict__ rs) {
  const int b = blockIdx.y;
  const int l = threadIdx.x & 63;
  const int wv = threadIdx.x >> 6;
  const int j = blockIdx.x * 64 + l;
  float phv[64];
  const float4* p4 = (const float4*)(ph + ((size_t)b * kN + j) * kC);
#pragma unroll
  for (int q = 0; q < 16; ++q) {
    const float4 t = p4[q];
    phv[4 * q] = t.x; phv[4 * q + 1] = t.y; phv[4 * q + 2] = t.z; phv[4 * q + 3] = t.w;
  }
  float s = 0.f;
  const int i0 = wv * (kN / 4), i1 = i0 + kN / 4;
  for (int i = i0; i < i1; ++i) {
    const float* tr = th + ((size_t)b * kN + i) * kC;  // wave-uniform -> s_load
    float f = 0.f;
#pragma unroll
    for (int c = 0; c < 64; ++c) f += tr[c] * phv[c];
    s += __expf(f - 20.f);
  }
  __shared__ float red[4][64];
  red[wv][l] = s;
  __syncthreads();
  if (threadIdx.x < 64) {
    const float t = red[0][threadIdx.x] + red[1][threadIdx.x] +
                    red[2][threadIdx.x] + red[3][threadIdx.x];
    rs[(size_t)b * kN + blockIdx.x * 64 + threadIdx.x] = 1.0f / t;
  }
}

// ---- pass B: yT[b][i][c] = sum_j exp(th_i.ph_j - 20) * rs[j] * g[j][c]
__global__ __launch_bounds__(256) void k_passb(const float* __restrict__ th,
                                               const float* __restrict__ ph,
                                               const float* __restrict__ g,
                                               const float* __restrict__ rs,
                                               float* __restrict__ yT) {
  const int b = blockIdx.y;
  const int l = threadIdx.x & 63;
  const int wv = threadIdx.x >> 6;
  const int i = blockIdx.x * 64 + l;
  float thv[64];
  const float4* t4 = (const float4*)(th + ((size_t)b * kN + i) * kC);
#pragma unroll
  for (int q = 0; q < 16; ++q) {
    const float4 t = t4[q];
    thv[4 * q] = t.x; thv[4 * q + 1] = t.y; thv[4 * q + 2] = t.z; thv[4 * q + 3] = t.w;
  }
  float acc[64];
#pragma unroll
  for (int c = 0; c < 64; ++c) acc[c] = 0.f;
  const int j0 = wv * (kN / 4), j1 = j0 + kN / 4;
  for (int j = j0; j < j1; ++j) {
    const float* pr = ph + ((size_t)b * kN + j) * kC;  // wave-uniform
    float f = 0.f;
#pragma unroll
    for (int c = 0; c < 64; ++c) f += pr[c] * thv[c];
    const float P = __expf(f - 20.f) * rs[(size_t)b * kN + j];
    const float* gr = g + ((size_t)b * kN + j) * kC;   // wave-uniform
#pragma unroll
    for (int c = 0; c < 64; ++c) acc[c] += P * gr[c];
  }
  // combine the 4 j-chunk partials through LDS (16 KB)
  __shared__ float red[4][64][16];
  for (int ch = 0; ch < 4; ++ch) {
#pragma unroll
    for (int k = 0; k < 16; ++k) red[wv][l][k] = acc[ch * 16 + k];
    __syncthreads();
    if (wv == 0) {
#pragma unroll
      for (int k = 0; k < 16; ++k) {
        const float v = red[0][l][k] + red[1][l][k] + red[2][l][k] + red[3][l][k];
        yT[((size_t)b * kN + i) * kC + ch * 16 + k] = v;
      }
    }
    __syncthreads();
  }
}

// ---- z[b][o][n] = sum_c wWt[c][o]*yT[b][n][c] + prelu(x1) + x1
__global__ __launch_bounds__(64) void k_wy(const float* __restrict__ yT,
                                           const float* __restrict__ wWt,
                                           const float* __restrict__ x1,
                                           const float* __restrict__ alphap,
                                           float* __restrict__ z) {
  const int b = blockIdx.y;
  const int n = blockIdx.x * 64 + threadIdx.x;
  const float alpha = alphap[0];
  float acc[64];
#pragma unroll
  for (int o = 0; o < 64; ++o) acc[o] = 0.f;
  const float4* y4 = (const float4*)(yT + ((size_t)b * kN + n) * kC);
#pragma unroll
  for (int cq = 0; cq < 16; ++cq) {
    const float4 t = y4[cq];
    const float* wr = wWt + cq * 4 * 64;
    FMA64(wr, t.x);
    FMA64(wr + 64, t.y);
    FMA64(wr + 128, t.z);
    FMA64(wr + 192, t.w);
  }
#pragma unroll
  for (int o = 0; o < 64; ++o) {
    const size_t idx = ((size_t)b * kC + o) * kN + n;
    const float xv = x1[idx];
    const float p = xv >= 0.f ? xv : alpha * xv;
    z[idx] = acc[o] + p + xv;
  }
}

extern "C" void kernel_launch(void* const* d_in, const int* in_sizes, int n_in,
                              void* d_out, int out_size, void* d_ws, size_t ws_size,
                              hipStream_t stream) {
  const float* x      = (const float*)d_in[0];
  const float* w1     = (const float*)d_in[1];
  const float* w2     = (const float*)d_in[2];
  const float* wg     = (const float*)d_in[3];
  const float* wth    = (const float*)d_in[4];
  const float* wph    = (const float*)d_in[5];
  const float* wWm    = (const float*)d_in[6];
  const float* alphap = (const float*)d_in[7];
  float* out = (float*)d_out;
  float* ws = (float*)d_ws;

  const size_t SZ = (size_t)kB * kC * kN;  // 819200
  float* x1  = ws;                 // [B][C][N] conv1 raw (residual source)
  float* pT  = ws + SZ;            // [B][N][C] prelu(conv1); reused as yT
  float* mb  = ws + 2 * SZ;        // th, ph, g: [3][B][N][C]
  float* th  = mb;
  float* ph  = mb + SZ;
  float* g   = mb + 2 * SZ;
  float* rs  = ws + 5 * SZ;        // [B][N] reciprocal column sums
  float* w1t = rs + (size_t)kB * kN;
  float* w2t = w1t + kC * kC * 9;
  float* wt3 = w2t + kC * kC * 9;  // [wth^T, wph^T, wg^T]
  float* wWt = wt3 + 3 * kC * kC;
  float* z   = th;                 // reuse th after pass B

  k_prep<<<144, 256, 0, stream>>>(w1, w2, wg, wth, wph, wWm, w1t, w2t,
                                  wt3, wt3 + kC * kC, wt3 + 2 * kC * kC, wWt);
  k_conv3x3<0><<<dim3(25, 4, kB), 256, 0, stream>>>(x, w1t, alphap, x1, pT);
  k_pw3<<<dim3(kN / 64, kB, 3), 64, 0, stream>>>(pT, wt3, mb);
  k_colstat<<<dim3(kN / 64, kB), 256, 0, stream>>>(th, ph, rs);
  k_passb<<<dim3(kN / 64, kB), 256, 0, stream>>>(th, ph, g, rs, pT);
  k_wy<<<dim3(kN / 64, kB), 64, 0, stream>>>(pT, wWt, x1, alphap, z);
  k_conv3x3<1><<<dim3(25, 4, kB), 256, 0, stream>>>(z, w2t, alphap, out, nullptr);
}

// Round 2
// 462.842 us; speedup vs baseline: 8.9033x; 8.9033x over previous
//
#include <hip/hip_runtime.h>
#include <hip/hip_bf16.h>
#include <cstddef>

// NLBasicBlock fused pipeline, round 2: MFMA nonlocal block.
// Softmax over dim=1 (columns) => rs_j = 1/sum_i exp(f_ij - 20) precomputed,
// folded into g' = g * rs (channel-major). Then y^T = g'^T . exp(phi.theta^T - 20)
// via two bf16 MFMA passes; f never materialized.

constexpr int kB = 2, kC = 64, kH = 80, kW = 80, kN = kH * kW;
constexpr float kLOG2E = 1.4426950408889634f;
constexpr float kSHIFT = 28.853900817779268f;  // 20 * log2(e)

typedef __attribute__((ext_vector_type(8))) short short8;
typedef __attribute__((ext_vector_type(4))) float f32x4;

__device__ __forceinline__ int refl(int i, int n) {
  return i < 0 ? -i : (i >= n ? 2 * n - 2 - i : i);
}

__device__ __forceinline__ uint pkbf(float a, float b) {
  union { __hip_bfloat162 h; uint u; } x;
  x.h.x = __float2bfloat16(a);
  x.h.y = __float2bfloat16(b);
  return x.u;
}

#define FMA64(wrp, xv)                                   \
  {                                                      \
    _Pragma("unroll") for (int o_ = 0; o_ < 64; ++o_)    \
        acc[o_] += (wrp)[o_] * (xv);                     \
  }

// ---- weight transposes: w3x3 [o][ci][9] -> [ci][9][o]; w1x1 [o][c] -> [c][o]
__global__ void k_prep(const float* __restrict__ w1, const float* __restrict__ w2,
                       const float* __restrict__ wg, const float* __restrict__ wth,
                       const float* __restrict__ wph, const float* __restrict__ wWm,
                       float* __restrict__ w1t, float* __restrict__ w2t,
                       float* __restrict__ wtht, float* __restrict__ wpht,
                       float* __restrict__ wgt, float* __restrict__ wWt) {
  int idx = blockIdx.x * 256 + threadIdx.x;
  if (idx < kC * kC * 9) {
    int o = idx / (kC * 9);
    int r = idx % (kC * 9);
    int ci = r / 9, tap = r % 9;
    int d = (ci * 9 + tap) * kC + o;
    w1t[d] = w1[idx];
    w2t[d] = w2[idx];
  }
  if (idx < kC * kC) {
    int o = idx / kC, c = idx % kC;
    int d = c * kC + o;
    wtht[d] = wth[idx];
    wpht[d] = wph[idx];
    wgt[d] = wg[idx];
    wWt[d] = wWm[idx];
  }
}

// ---- 3x3 reflect conv. MODE 0: raw conv -> dst_raw [B][C][N] + prelu
// pixel-major -> dst_pt [B][N][C]. MODE 1: prelu -> dst_raw only.
template <int MODE>
__global__ __launch_bounds__(256) void k_conv3x3(
    const float* __restrict__ src, const float* __restrict__ wt,
    const float* __restrict__ alphap, float* __restrict__ dst_raw,
    float* __restrict__ dst_pt) {
  const int tile = blockIdx.x;
  const int cog = blockIdx.y;
  const int b = blockIdx.z;
  const int ty0 = (tile / 5) * 16, tx0 = (tile % 5) * 16;
  const int tid = threadIdx.x;
  const int ty = tid / 16, tx = tid % 16;
  const float alpha = alphap[0];

  __shared__ float lds[32 * 18 * 18];
  float acc[16];
#pragma unroll
  for (int o = 0; o < 16; ++o) acc[o] = 0.f;

  for (int chunk = 0; chunk < 2; ++chunk) {
    const int ci0 = chunk * 32;
    __syncthreads();
    for (int idx = tid; idx < 32 * 324; idx += 256) {
      int cc = idx / 324;
      int r = idx % 324;
      int hh = r / 18, ww = r % 18;
      int gh = refl(ty0 - 1 + hh, kH);
      int gw = refl(tx0 - 1 + ww, kW);
      lds[idx] = src[(((size_t)b * kC + ci0 + cc) * kH + gh) * kW + gw];
    }
    __syncthreads();
    for (int cc = 0; cc < 32; ++cc) {
#pragma unroll
      for (int tap = 0; tap < 9; ++tap) {
        const int dh = tap / 3, dw = tap % 3;
        const float xv = lds[cc * 324 + (ty + dh) * 18 + (tx + dw)];
        const float* wr = wt + ((size_t)(ci0 + cc) * 9 + tap) * kC + cog * 16;
#pragma unroll
        for (int o = 0; o < 16; ++o) acc[o] += wr[o] * xv;
      }
    }
  }

  const int n = (ty0 + ty) * kW + (tx0 + tx);
#pragma unroll
  for (int o = 0; o < 16; ++o) {
    const int co = cog * 16 + o;
    const float v = acc[o];
    const float p = v >= 0.f ? v : alpha * v;
    if (MODE == 0) {
      dst_raw[((size_t)b * kC + co) * kN + n] = v;
      dst_pt[((size_t)b * kN + n) * kC + co] = p;
    } else {
      dst_raw[((size_t)b * kC + co) * kN + n] = p;
    }
  }
}

// ---- three 1x1 convs -> bf16 pixel-major: outb[m][b][n][o]
__global__ __launch_bounds__(64) void k_pw3(const float* __restrict__ pT,
                                            const float* __restrict__ wt3,
                                            __hip_bfloat16* __restrict__ outb) {
  const int m = blockIdx.z, b = blockIdx.y;
  const int n = blockIdx.x * 64 + threadIdx.x;
  const float* wt = wt3 + (size_t)m * kC * kC;
  const float4* p4 = (const float4*)(pT + ((size_t)b * kN + n) * kC);
  float acc[64];
#pragma unroll
  for (int o = 0; o < 64; ++o) acc[o] = 0.f;
#pragma unroll
  for (int cq = 0; cq < 16; ++cq) {
    const float4 t = p4[cq];
    const float* wr = wt + cq * 4 * 64;
    FMA64(wr, t.x);
    FMA64(wr + 64, t.y);
    FMA64(wr + 128, t.z);
    FMA64(wr + 192, t.w);
  }
  uint* d32 = (uint*)(outb + (((size_t)m * kB + b) * kN + n) * kC);
#pragma unroll
  for (int q = 0; q < 32; ++q) d32[q] = pkbf(acc[2 * q], acc[2 * q + 1]);
}

// ---- column sums: partial[b][ic][j] = sum_{i in chunk} exp(theta_i.phi_j - 20)
// MFMA S' = phi . theta^T : D col = i (lane&15), row = j (hi*4+reg)
__global__ __launch_bounds__(256) void k_colstat(
    const __hip_bfloat16* __restrict__ th, const __hip_bfloat16* __restrict__ ph,
    float* __restrict__ partial) {
  const int b = blockIdx.z, ic = blockIdx.y;
  const int lane = threadIdx.x & 63, w = threadIdx.x >> 6;
  const int il = lane & 15, hi = lane >> 4;
  const int j0 = blockIdx.x * 64 + w * 16;

  const short8 af0 = *(const short8*)&ph[((size_t)b * kN + j0 + il) * kC + hi * 8];
  const short8 af1 = *(const short8*)&ph[((size_t)b * kN + j0 + il) * kC + 32 + hi * 8];
  const __hip_bfloat16* thB = th + (size_t)b * kN * kC;

  float cs[4] = {0.f, 0.f, 0.f, 0.f};
  int i = ic * (kN / 4);
  for (int s = 0; s < kN / 4 / 16; ++s, i += 16) {
    const short8 bf0 = *(const short8*)&thB[(size_t)(i + il) * kC + hi * 8];
    const short8 bf1 = *(const short8*)&thB[(size_t)(i + il) * kC + 32 + hi * 8];
    f32x4 acc = {0.f, 0.f, 0.f, 0.f};
    acc = __builtin_amdgcn_mfma_f32_16x16x32_bf16(af0, bf0, acc, 0, 0, 0);
    acc = __builtin_amdgcn_mfma_f32_16x16x32_bf16(af1, bf1, acc, 0, 0, 0);
#pragma unroll
    for (int r = 0; r < 4; ++r)
      cs[r] += exp2f(fmaf(acc[r], kLOG2E, -kSHIFT));
  }
#pragma unroll
  for (int r = 0; r < 4; ++r) {
    cs[r] += __shfl_xor(cs[r], 1);
    cs[r] += __shfl_xor(cs[r], 2);
    cs[r] += __shfl_xor(cs[r], 4);
    cs[r] += __shfl_xor(cs[r], 8);
  }
  if (il == 0) {
    float* p = partial + ((size_t)(b * 4 + ic)) * kN + j0 + hi * 4;
#pragma unroll
    for (int r = 0; r < 4; ++r) p[r] = cs[r];
  }
}

// ---- gT[b][c][j] = bf16( g[b][j][c] * 1/colsum[b][j] )
__global__ __launch_bounds__(256) void k_gscale(
    const __hip_bfloat16* __restrict__ gb, const float* __restrict__ partial,
    __hip_bfloat16* __restrict__ gT) {
  const int b = blockIdx.y;
  const int j0 = blockIdx.x * 64;
  const int t = threadIdx.x;
  __shared__ ushort tile[64][66];
  __shared__ float rsv[64];
  if (t < 64) {
    const int j = j0 + t;
    float cs = partial[(size_t)(b * 4 + 0) * kN + j] +
               partial[(size_t)(b * 4 + 1) * kN + j] +
               partial[(size_t)(b * 4 + 2) * kN + j] +
               partial[(size_t)(b * 4 + 3) * kN + j];
    rsv[t] = 1.0f / cs;
  }
  {
    const int jl = t >> 2, cseg = (t & 3) * 16;
    const ushort* src = (const ushort*)&gb[((size_t)b * kN + j0 + jl) * kC + cseg];
    union { short8 v; ushort u[8]; } u0, u1;
    u0.v = *(const short8*)src;
    u1.v = *(const short8*)(src + 8);
#pragma unroll
    for (int k = 0; k < 8; ++k) {
      tile[jl][cseg + k] = u0.u[k];
      tile[jl][cseg + 8 + k] = u1.u[k];
    }
  }
  __syncthreads();
  const int c = t >> 2, jseg = (t & 3) * 16;
  union { short8 v; ushort u[8]; } o0, o1;
#pragma unroll
  for (int k = 0; k < 16; ++k) {
    const int j = jseg + k;
    const float gv = __uint_as_float((uint)tile[j][c] << 16);
    union { __hip_bfloat16 h; ushort us; } cv;
    cv.h = __float2bfloat16(gv * rsv[j]);
    if (k < 8) o0.u[k] = cv.us; else o1.u[k - 8] = cv.us;
  }
  short8* dst = (short8*)&gT[((size_t)b * kC + c) * kN + j0 + jseg];
  dst[0] = o0.v;
  dst[1] = o1.v;
}

// ---- pass B: y[b][c][i] = sum_j exp(th_i.ph_j - 20) * gT[c][j]
// Each block: one 16-i tile; 4 waves split j into quarters; LDS-reduce.
__global__ __launch_bounds__(256) void k_passb(
    const __hip_bfloat16* __restrict__ th, const __hip_bfloat16* __restrict__ ph,
    const __hip_bfloat16* __restrict__ gT, float* __restrict__ y) {
  const int b = blockIdx.y;
  const int lane = threadIdx.x & 63, w = threadIdx.x >> 6;
  const int il = lane & 15, hi = lane >> 4;
  const int i0 = blockIdx.x * 16;

  __shared__ ushort plds[4 * 512];   // per-wave 32x16 bf16 P tile, swizzled
  __shared__ float red[4][16][64];

  ushort* pw = plds + w * 512;
  uint* pw32 = (uint*)pw;
  const int swz = (il & 3) << 3;

  // theta B-fragments (col i = il, rows c = hi*8..), fixed for whole kernel
  const short8 tb0 = *(const short8*)&th[((size_t)b * kN + i0 + il) * kC + hi * 8];
  const short8 tb1 = *(const short8*)&th[((size_t)b * kN + i0 + il) * kC + 32 + hi * 8];

  f32x4 accy[4];
#pragma unroll
  for (int ct = 0; ct < 4; ++ct) accy[ct] = {0.f, 0.f, 0.f, 0.f};

  const __hip_bfloat16* phB = ph + (size_t)b * kN * kC;
  const __hip_bfloat16* gTB = gT + (size_t)b * kC * kN;

  const int jend = (w + 1) * (kN / 4);
  for (int jg = w * (kN / 4); jg < jend; jg += 32) {
#pragma unroll
    for (int jj = 0; jj < 2; ++jj) {
      const int jrow = jg + jj * 16 + il;
      const short8 pa0 = *(const short8*)&phB[(size_t)jrow * kC + hi * 8];
      const short8 pa1 = *(const short8*)&phB[(size_t)jrow * kC + 32 + hi * 8];
      f32x4 s = {0.f, 0.f, 0.f, 0.f};
      s = __builtin_amdgcn_mfma_f32_16x16x32_bf16(pa0, tb0, s, 0, 0, 0);
      s = __builtin_amdgcn_mfma_f32_16x16x32_bf16(pa1, tb1, s, 0, 0, 0);
      const float p0 = exp2f(fmaf(s[0], kLOG2E, -kSHIFT));
      const float p1 = exp2f(fmaf(s[1], kLOG2E, -kSHIFT));
      const float p2 = exp2f(fmaf(s[2], kLOG2E, -kSHIFT));
      const float p3 = exp2f(fmaf(s[3], kLOG2E, -kSHIFT));
      const int jl = jj * 16 + hi * 4;
      pw32[(il * 32 + ((jl + 0) ^ swz)) >> 1] = pkbf(p0, p1);
      pw32[(il * 32 + ((jl + 2) ^ swz)) >> 1] = pkbf(p2, p3);
    }
    // B2 fragment: col i = il, rows j = hi*8.. (swizzle-inverted read)
    const short8 pb = *(const short8*)&pw[il * 32 + ((hi * 8) ^ swz)];
#pragma unroll
    for (int ct = 0; ct < 4; ++ct) {
      const short8 ga =
          *(const short8*)&gTB[(size_t)(ct * 16 + il) * kN + jg + hi * 8];
      accy[ct] = __builtin_amdgcn_mfma_f32_16x16x32_bf16(ga, pb, accy[ct], 0, 0, 0);
    }
  }

  // cross-wave reduce (4 j-partials), wave0 writes y channel-major
#pragma unroll
  for (int ct = 0; ct < 4; ++ct)
#pragma unroll
    for (int r = 0; r < 4; ++r) red[w][ct * 4 + r][lane] = accy[ct][r];
  __syncthreads();
  if (w == 0) {
#pragma unroll
    for (int k = 0; k < 16; ++k) {
      const float v = red[0][k][lane] + red[1][k][lane] + red[2][k][lane] +
                      red[3][k][lane];
      const int c = (k >> 2) * 16 + hi * 4 + (k & 3);
      y[((size_t)b * kC + c) * kN + i0 + il] = v;
    }
  }
}

// ---- z[b][o][n] = sum_c wWt[c][o]*y[b][c][n] + prelu(x1) + x1
__global__ __launch_bounds__(64) void k_wy(const float* __restrict__ y,
                                           const float* __restrict__ wWt,
                                           const float* __restrict__ x1,
                                           const float* __restrict__ alphap,
                                           float* __restrict__ z) {
  const int b = blockIdx.y;
  const int n = blockIdx.x * 64 + threadIdx.x;
  const float alpha = alphap[0];
  float acc[64];
#pragma unroll
  for (int o = 0; o < 64; ++o) acc[o] = 0.f;
  for (int c = 0; c < 64; ++c) {
    const float yv = y[((size_t)b * kC + c) * kN + n];
    const float* wr = wWt + c * 64;
    FMA64(wr, yv);
  }
#pragma unroll
  for (int o = 0; o < 64; ++o) {
    const size_t idx = ((size_t)b * kC + o) * kN + n;
    const float xv = x1[idx];
    const float p = xv >= 0.f ? xv : alpha * xv;
    z[idx] = acc[o] + p + xv;
  }
}

extern "C" void kernel_launch(void* const* d_in, const int* in_sizes, int n_in,
                              void* d_out, int out_size, void* d_ws, size_t ws_size,
                              hipStream_t stream) {
  const float* x      = (const float*)d_in[0];
  const float* w1     = (const float*)d_in[1];
  const float* w2     = (const float*)d_in[2];
  const float* wg     = (const float*)d_in[3];
  const float* wth    = (const float*)d_in[4];
  const float* wph    = (const float*)d_in[5];
  const float* wWm    = (const float*)d_in[6];
  const float* alphap = (const float*)d_in[7];
  float* out = (float*)d_out;

  const size_t SZ = (size_t)kB * kC * kN;  // 819200 elements
  float* x1 = (float*)d_ws;                       // [B][C][N] f32
  float* pT = x1 + SZ;                            // [B][N][C] f32; reused as y
  __hip_bfloat16* thb = (__hip_bfloat16*)(pT + SZ);  // [B][N][C] bf16
  __hip_bfloat16* phb = thb + SZ;
  __hip_bfloat16* gb  = phb + SZ;
  __hip_bfloat16* gT  = gb + SZ;                  // [B][C][N] bf16 (rs-scaled)
  float* partial = (float*)(gT + SZ);             // [B][4][N] f32
  float* w1t = partial + (size_t)kB * 4 * kN;
  float* w2t = w1t + kC * kC * 9;
  float* wt3 = w2t + kC * kC * 9;
  float* wWt = wt3 + 3 * kC * kC;
  float* y = pT;                // reuse (pT dead after k_pw3)
  float* z = (float*)thb;       // reuse (thb/phb dead after k_passb; 4.9MB >= 3.3MB)

  k_prep<<<144, 256, 0, stream>>>(w1, w2, wg, wth, wph, wWm, w1t, w2t,
                                  wt3, wt3 + kC * kC, wt3 + 2 * kC * kC, wWt);
  k_conv3x3<0><<<dim3(25, 4, kB), 256, 0, stream>>>(x, w1t, alphap, x1, pT);
  k_pw3<<<dim3(kN / 64, kB, 3), 64, 0, stream>>>(pT, wt3, thb);
  k_colstat<<<dim3(kN / 64, 4, kB), 256, 0, stream>>>(thb, phb, partial);
  k_gscale<<<dim3(kN / 64, kB), 256, 0, stream>>>(gb, partial, gT);
  k_passb<<<dim3(kN / 16, kB), 256, 0, stream>>>(thb, phb, gT, y);
  k_wy<<<dim3(kN / 64, kB), 64, 0, stream>>>(y, wWt, x1, alphap, z);
  k_conv3x3<1><<<dim3(25, 4, kB), 256, 0, stream>>>(z, w2t, alphap, out, nullptr);
}

// Round 3
// 434.516 us; speedup vs baseline: 9.4837x; 1.0652x over previous
//
#include <hip/hip_runtime.h>
#include <hip/hip_bf16.h>
#include <cstddef>

// NLBasicBlock fused, round 3.
// Nonlocal: rs_j = 1/sum_i exp(f_ij-20) folded into gT (channel-major).
// passb: sigma-permuted phi rows make the QK^T MFMA output land exactly in
// the PV B-fragment register layout (no LDS P tile, no shuffles).
// W_y GEMM + prelu(x1) + x1 residuals fused into passb epilogue.

constexpr int kB = 2, kC = 64, kH = 80, kW = 80, kN = kH * kW;
constexpr float kLOG2E = 1.4426950408889634f;
constexpr float kSHIFT = 28.853900817779268f;  // 20 * log2(e)

typedef __attribute__((ext_vector_type(8))) short short8;
typedef __attribute__((ext_vector_type(4))) float f32x4;

__device__ __forceinline__ int refl(int i, int n) {
  return i < 0 ? -i : (i >= n ? 2 * n - 2 - i : i);
}

__device__ __forceinline__ uint pkbf(float a, float b) {
  union { __hip_bfloat162 h; uint u; } x;
  x.h.x = __float2bfloat16(a);
  x.h.y = __float2bfloat16(b);
  return x.u;
}

#define FMA64(wrp, xv)                                   \
  {                                                      \
    _Pragma("unroll") for (int o_ = 0; o_ < 64; ++o_)    \
        acc[o_] += (wrp)[o_] * (xv);                     \
  }

// ---- weight prep: w3x3 [o][ci][9] -> [ci][9][o]; w1x1 [o][c] -> [c][o] f32;
// wW -> bf16 copy in original [o][c] layout (A-operand of fused W_y MFMA).
__global__ void k_prep(const float* __restrict__ w1, const float* __restrict__ w2,
                       const float* __restrict__ wg, const float* __restrict__ wth,
                       const float* __restrict__ wph, const float* __restrict__ wWm,
                       float* __restrict__ w1t, float* __restrict__ w2t,
                       float* __restrict__ wtht, float* __restrict__ wpht,
                       float* __restrict__ wgt, __hip_bfloat16* __restrict__ wWb) {
  int idx = blockIdx.x * 256 + threadIdx.x;
  if (idx < kC * kC * 9) {
    int o = idx / (kC * 9);
    int r = idx % (kC * 9);
    int ci = r / 9, tap = r % 9;
    int d = (ci * 9 + tap) * kC + o;
    w1t[d] = w1[idx];
    w2t[d] = w2[idx];
  }
  if (idx < kC * kC) {
    int o = idx / kC, c = idx % kC;
    int d = c * kC + o;
    wtht[d] = wth[idx];
    wpht[d] = wph[idx];
    wgt[d] = wg[idx];
    wWb[idx] = __float2bfloat16(wWm[idx]);
  }
}

// ---- 3x3 reflect conv. MODE 0: raw conv -> dst_raw [B][C][N] + prelu
// pixel-major -> dst_pt [B][N][C]. MODE 1: prelu -> dst_raw only.
template <int MODE>
__global__ __launch_bounds__(256) void k_conv3x3(
    const float* __restrict__ src, const float* __restrict__ wt,
    const float* __restrict__ alphap, float* __restrict__ dst_raw,
    float* __restrict__ dst_pt) {
  const int tile = blockIdx.x;
  const int cog = blockIdx.y;
  const int b = blockIdx.z;
  const int ty0 = (tile / 5) * 16, tx0 = (tile % 5) * 16;
  const int tid = threadIdx.x;
  const int ty = tid / 16, tx = tid % 16;
  const float alpha = alphap[0];

  __shared__ float lds[32 * 18 * 18];
  float acc[16];
#pragma unroll
  for (int o = 0; o < 16; ++o) acc[o] = 0.f;

  for (int chunk = 0; chunk < 2; ++chunk) {
    const int ci0 = chunk * 32;
    __syncthreads();
    for (int idx = tid; idx < 32 * 324; idx += 256) {
      int cc = idx / 324;
      int r = idx % 324;
      int hh = r / 18, ww = r % 18;
      int gh = refl(ty0 - 1 + hh, kH);
      int gw = refl(tx0 - 1 + ww, kW);
      lds[idx] = src[(((size_t)b * kC + ci0 + cc) * kH + gh) * kW + gw];
    }
    __syncthreads();
    for (int cc = 0; cc < 32; ++cc) {
#pragma unroll
      for (int tap = 0; tap < 9; ++tap) {
        const int dh = tap / 3, dw = tap % 3;
        const float xv = lds[cc * 324 + (ty + dh) * 18 + (tx + dw)];
        const float* wr = wt + ((size_t)(ci0 + cc) * 9 + tap) * kC + cog * 16;
#pragma unroll
        for (int o = 0; o < 16; ++o) acc[o] += wr[o] * xv;
      }
    }
  }

  const int n = (ty0 + ty) * kW + (tx0 + tx);
#pragma unroll
  for (int o = 0; o < 16; ++o) {
    const int co = cog * 16 + o;
    const float v = acc[o];
    const float p = v >= 0.f ? v : alpha * v;
    if (MODE == 0) {
      dst_raw[((size_t)b * kC + co) * kN + n] = v;
      dst_pt[((size_t)b * kN + n) * kC + co] = p;
    } else {
      dst_raw[((size_t)b * kC + co) * kN + n] = p;
    }
  }
}

// ---- three 1x1 convs -> bf16 pixel-major: outb[m][b][n][o]
__global__ __launch_bounds__(64) void k_pw3(const float* __restrict__ pT,
                                            const float* __restrict__ wt3,
                                            __hip_bfloat16* __restrict__ outb) {
  const int m = blockIdx.z, b = blockIdx.y;
  const int n = blockIdx.x * 64 + threadIdx.x;
  const float* wt = wt3 + (size_t)m * kC * kC;
  const float4* p4 = (const float4*)(pT + ((size_t)b * kN + n) * kC);
  float acc[64];
#pragma unroll
  for (int o = 0; o < 64; ++o) acc[o] = 0.f;
#pragma unroll
  for (int cq = 0; cq < 16; ++cq) {
    const float4 t = p4[cq];
    const float* wr = wt + cq * 4 * 64;
    FMA64(wr, t.x);
    FMA64(wr + 64, t.y);
    FMA64(wr + 128, t.z);
    FMA64(wr + 192, t.w);
  }
  uint* d32 = (uint*)(outb + (((size_t)m * kB + b) * kN + n) * kC);
#pragma unroll
  for (int q = 0; q < 32; ++q) d32[q] = pkbf(acc[2 * q], acc[2 * q + 1]);
}

// ---- column sums: partial[b][ic][j] = sum_{i in chunk} exp(theta_i.phi_j-20)
// S' = phi.theta^T : D col = i (lane&15), row = j (hi*4+reg). i-unrolled x2.
__global__ __launch_bounds__(256, 3) void k_colstat(
    const __hip_bfloat16* __restrict__ th, const __hip_bfloat16* __restrict__ ph,
    float* __restrict__ partial) {
  const int b = blockIdx.z, ic = blockIdx.y;
  const int lane = threadIdx.x & 63, w = threadIdx.x >> 6;
  const int il = lane & 15, hi = lane >> 4;
  const int j0 = blockIdx.x * 64 + w * 16;

  const short8 af0 = *(const short8*)&ph[((size_t)b * kN + j0 + il) * kC + hi * 8];
  const short8 af1 = *(const short8*)&ph[((size_t)b * kN + j0 + il) * kC + 32 + hi * 8];
  const __hip_bfloat16* thB = th + (size_t)b * kN * kC;

  float cs[4] = {0.f, 0.f, 0.f, 0.f};
  int i = ic * (kN / 4);
  for (int s = 0; s < kN / 4 / 32; ++s, i += 32) {
    const short8 b0a = *(const short8*)&thB[(size_t)(i + il) * kC + hi * 8];
    const short8 b1a = *(const short8*)&thB[(size_t)(i + il) * kC + 32 + hi * 8];
    const short8 b0b = *(const short8*)&thB[(size_t)(i + 16 + il) * kC + hi * 8];
    const short8 b1b = *(const short8*)&thB[(size_t)(i + 16 + il) * kC + 32 + hi * 8];
    f32x4 sa = {0.f, 0.f, 0.f, 0.f};
    f32x4 sb = {0.f, 0.f, 0.f, 0.f};
    sa = __builtin_amdgcn_mfma_f32_16x16x32_bf16(af0, b0a, sa, 0, 0, 0);
    sa = __builtin_amdgcn_mfma_f32_16x16x32_bf16(af1, b1a, sa, 0, 0, 0);
    sb = __builtin_amdgcn_mfma_f32_16x16x32_bf16(af0, b0b, sb, 0, 0, 0);
    sb = __builtin_amdgcn_mfma_f32_16x16x32_bf16(af1, b1b, sb, 0, 0, 0);
#pragma unroll
    for (int r = 0; r < 4; ++r)
      cs[r] += exp2f(fmaf(sa[r], kLOG2E, -kSHIFT)) +
               exp2f(fmaf(sb[r], kLOG2E, -kSHIFT));
  }
#pragma unroll
  for (int r = 0; r < 4; ++r) {
    cs[r] += __shfl_xor(cs[r], 1);
    cs[r] += __shfl_xor(cs[r], 2);
    cs[r] += __shfl_xor(cs[r], 4);
    cs[r] += __shfl_xor(cs[r], 8);
  }
  if (il == 0) {
    float* p = partial + ((size_t)(b * 4 + ic)) * kN + j0 + hi * 4;
#pragma unroll
    for (int r = 0; r < 4; ++r) p[r] = cs[r];
  }
}

// ---- gT[b][c][j] = bf16( g[b][j][c] * 1/colsum[b][j] )
__global__ __launch_bounds__(256) void k_gscale(
    const __hip_bfloat16* __restrict__ gb, const float* __restrict__ partial,
    __hip_bfloat16* __restrict__ gT) {
  const int b = blockIdx.y;
  const int j0 = blockIdx.x * 64;
  const int t = threadIdx.x;
  __shared__ ushort tile[64][66];
  __shared__ float rsv[64];
  if (t < 64) {
    const int j = j0 + t;
    float cs = partial[(size_t)(b * 4 + 0) * kN + j] +
               partial[(size_t)(b * 4 + 1) * kN + j] +
               partial[(size_t)(b * 4 + 2) * kN + j] +
               partial[(size_t)(b * 4 + 3) * kN + j];
    rsv[t] = 1.0f / cs;
  }
  {
    const int jl = t >> 2, cseg = (t & 3) * 16;
    const ushort* src = (const ushort*)&gb[((size_t)b * kN + j0 + jl) * kC + cseg];
    union { short8 v; ushort u[8]; } u0, u1;
    u0.v = *(const short8*)src;
    u1.v = *(const short8*)(src + 8);
#pragma unroll
    for (int k = 0; k < 8; ++k) {
      tile[jl][cseg + k] = u0.u[k];
      tile[jl][cseg + 8 + k] = u1.u[k];
    }
  }
  __syncthreads();
  const int c = t >> 2, jseg = (t & 3) * 16;
  union { short8 v; ushort u[8]; } o0, o1;
#pragma unroll
  for (int k = 0; k < 16; ++k) {
    const int j = jseg + k;
    const float gv = __uint_as_float((uint)tile[j][c] << 16);
    union { __hip_bfloat16 h; ushort us; } cv;
    cv.h = __float2bfloat16(gv * rsv[j]);
    if (k < 8) o0.u[k] = cv.us; else o1.u[k - 8] = cv.us;
  }
  short8* dst = (short8*)&gT[((size_t)b * kC + c) * kN + j0 + jseg];
  dst[0] = o0.v;
  dst[1] = o1.v;
}

// ---- fused pass B + W_y + residuals:
// z[b][o][n] = sum_c wW[o][c] * y[c][n] + prelu(x1) + x1,
// y[c][i] = sum_j exp(th_i.ph_j - 20) * gT[c][j]  (gT pre-scaled by rs_j).
// sigma trick: QK A-rows permuted so D regs (2 sub-MFMAs) = PV B-fragment.
__global__ __launch_bounds__(256, 3) void k_nl(
    const __hip_bfloat16* __restrict__ th, const __hip_bfloat16* __restrict__ ph,
    const __hip_bfloat16* __restrict__ gT, const __hip_bfloat16* __restrict__ wWb,
    const float* __restrict__ x1, const float* __restrict__ alphap,
    float* __restrict__ z) {
  const int b = blockIdx.y;
  const int lane = threadIdx.x & 63, w = threadIdx.x >> 6;
  const int il = lane & 15, hi = lane >> 4;
  const int i0 = blockIdx.x * 16;
  const int jbase = ((il >> 2) << 3) + (il & 3);  // sigma(row=il)

  __shared__ float red[4][16][64];
  __shared__ ushort ytile[16 * 72];  // [i][c] bf16, stride 72 (144B, 16-aligned)

  const short8 tb0 = *(const short8*)&th[((size_t)b * kN + i0 + il) * kC + hi * 8];
  const short8 tb1 = *(const short8*)&th[((size_t)b * kN + i0 + il) * kC + 32 + hi * 8];

  f32x4 accy[4];
#pragma unroll
  for (int ct = 0; ct < 4; ++ct) accy[ct] = {0.f, 0.f, 0.f, 0.f};

  const __hip_bfloat16* phB = ph + (size_t)b * kN * kC;
  const __hip_bfloat16* gTB = gT + (size_t)b * kC * kN;

  const int jend = (w + 1) * (kN / 4);
  for (int jg = w * (kN / 4); jg < jend; jg += 32) {
    const size_t r0 = (size_t)(jg + jbase) * kC;
    const size_t r1 = (size_t)(jg + jbase + 4) * kC;
    const short8 pa00 = *(const short8*)&phB[r0 + hi * 8];
    const short8 pa01 = *(const short8*)&phB[r0 + 32 + hi * 8];
    const short8 pa10 = *(const short8*)&phB[r1 + hi * 8];
    const short8 pa11 = *(const short8*)&phB[r1 + 32 + hi * 8];
    const short8 ga0 = *(const short8*)&gTB[(size_t)(il) * kN + jg + hi * 8];
    const short8 ga1 = *(const short8*)&gTB[(size_t)(16 + il) * kN + jg + hi * 8];
    const short8 ga2 = *(const short8*)&gTB[(size_t)(32 + il) * kN + jg + hi * 8];
    const short8 ga3 = *(const short8*)&gTB[(size_t)(48 + il) * kN + jg + hi * 8];
    f32x4 s0 = {0.f, 0.f, 0.f, 0.f};
    f32x4 s1 = {0.f, 0.f, 0.f, 0.f};
    s0 = __builtin_amdgcn_mfma_f32_16x16x32_bf16(pa00, tb0, s0, 0, 0, 0);
    s0 = __builtin_amdgcn_mfma_f32_16x16x32_bf16(pa01, tb1, s0, 0, 0, 0);
    s1 = __builtin_amdgcn_mfma_f32_16x16x32_bf16(pa10, tb0, s1, 0, 0, 0);
    s1 = __builtin_amdgcn_mfma_f32_16x16x32_bf16(pa11, tb1, s1, 0, 0, 0);
    const float e0 = exp2f(fmaf(s0[0], kLOG2E, -kSHIFT));
    const float e1 = exp2f(fmaf(s0[1], kLOG2E, -kSHIFT));
    const float e2 = exp2f(fmaf(s0[2], kLOG2E, -kSHIFT));
    const float e3 = exp2f(fmaf(s0[3], kLOG2E, -kSHIFT));
    const float e4 = exp2f(fmaf(s1[0], kLOG2E, -kSHIFT));
    const float e5 = exp2f(fmaf(s1[1], kLOG2E, -kSHIFT));
    const float e6 = exp2f(fmaf(s1[2], kLOG2E, -kSHIFT));
    const float e7 = exp2f(fmaf(s1[3], kLOG2E, -kSHIFT));
    short8 pb;
    uint* pw = (uint*)&pb;
    pw[0] = pkbf(e0, e1);
    pw[1] = pkbf(e2, e3);
    pw[2] = pkbf(e4, e5);
    pw[3] = pkbf(e6, e7);
    accy[0] = __builtin_amdgcn_mfma_f32_16x16x32_bf16(ga0, pb, accy[0], 0, 0, 0);
    accy[1] = __builtin_amdgcn_mfma_f32_16x16x32_bf16(ga1, pb, accy[1], 0, 0, 0);
    accy[2] = __builtin_amdgcn_mfma_f32_16x16x32_bf16(ga2, pb, accy[2], 0, 0, 0);
    accy[3] = __builtin_amdgcn_mfma_f32_16x16x32_bf16(ga3, pb, accy[3], 0, 0, 0);
  }

#pragma unroll
  for (int ct = 0; ct < 4; ++ct)
#pragma unroll
    for (int r = 0; r < 4; ++r) red[w][ct * 4 + r][lane] = accy[ct][r];
  __syncthreads();
  if (w == 0) {
#pragma unroll
    for (int k = 0; k < 16; k += 2) {
      const float va = red[0][k][lane] + red[1][k][lane] + red[2][k][lane] +
                       red[3][k][lane];
      const float vb = red[0][k + 1][lane] + red[1][k + 1][lane] +
                       red[2][k + 1][lane] + red[3][k + 1][lane];
      const int c0 = ((k >> 2) << 4) + hi * 4 + (k & 3);
      *(uint*)&ytile[il * 72 + c0] = pkbf(va, vb);
    }
  }
  __syncthreads();

  // fused W_y: out[o][i], o-chunk = w*16; A = wW[o][c] bf16, B = ytile[i][c]
  const short8 af0 = *(const short8*)&wWb[(size_t)(w * 16 + il) * kC + hi * 8];
  const short8 af1 = *(const short8*)&wWb[(size_t)(w * 16 + il) * kC + 32 + hi * 8];
  const short8 by0 = *(const short8*)&ytile[il * 72 + hi * 8];
  const short8 by1 = *(const short8*)&ytile[il * 72 + 32 + hi * 8];
  f32x4 o4 = {0.f, 0.f, 0.f, 0.f};
  o4 = __builtin_amdgcn_mfma_f32_16x16x32_bf16(af0, by0, o4, 0, 0, 0);
  o4 = __builtin_amdgcn_mfma_f32_16x16x32_bf16(af1, by1, o4, 0, 0, 0);
  const float alpha = alphap[0];
#pragma unroll
  for (int r = 0; r < 4; ++r) {
    const int o = w * 16 + hi * 4 + r;
    const size_t idx = ((size_t)b * kC + o) * kN + i0 + il;
    const float xv = x1[idx];
    const float p = xv >= 0.f ? xv : alpha * xv;
    z[idx] = o4[r] + p + xv;
  }
}

extern "C" void kernel_launch(void* const* d_in, const int* in_sizes, int n_in,
                              void* d_out, int out_size, void* d_ws, size_t ws_size,
                              hipStream_t stream) {
  const float* x      = (const float*)d_in[0];
  const float* w1     = (const float*)d_in[1];
  const float* w2     = (const float*)d_in[2];
  const float* wg     = (const float*)d_in[3];
  const float* wth    = (const float*)d_in[4];
  const float* wph    = (const float*)d_in[5];
  const float* wWm    = (const float*)d_in[6];
  const float* alphap = (const float*)d_in[7];
  float* out = (float*)d_out;

  const size_t SZ = (size_t)kB * kC * kN;  // 819200 elements
  float* x1 = (float*)d_ws;                          // [B][C][N] f32
  float* pT = x1 + SZ;                               // [B][N][C] f32; reused as z
  __hip_bfloat16* thb = (__hip_bfloat16*)(pT + SZ);  // [B][N][C] bf16
  __hip_bfloat16* phb = thb + SZ;
  __hip_bfloat16* gb  = phb + SZ;
  __hip_bfloat16* gT  = gb + SZ;                     // [B][C][N] bf16 (rs-scaled)
  float* partial = (float*)(gT + SZ);                // [B][4][N] f32
  float* w1t = partial + (size_t)kB * 4 * kN;
  float* w2t = w1t + kC * kC * 9;
  float* wt3 = w2t + kC * kC * 9;
  __hip_bfloat16* wWb = (__hip_bfloat16*)(wt3 + 3 * kC * kC);
  float* z = pT;  // pT dead after k_pw3

  k_prep<<<144, 256, 0, stream>>>(w1, w2, wg, wth, wph, wWm, w1t, w2t,
                                  wt3, wt3 + kC * kC, wt3 + 2 * kC * kC, wWb);
  k_conv3x3<0><<<dim3(25, 4, kB), 256, 0, stream>>>(x, w1t, alphap, x1, pT);
  k_pw3<<<dim3(kN / 64, kB, 3), 64, 0, stream>>>(pT, wt3, thb);
  k_colstat<<<dim3(kN / 64, 4, kB), 256, 0, stream>>>(thb, phb, partial);
  k_gscale<<<dim3(kN / 64, kB), 256, 0, stream>>>(gb, partial, gT);
  k_nl<<<dim3(kN / 16, kB), 256, 0, stream>>>(thb, phb, gT, wWb, x1, alphap, z);
  k_conv3x3<1><<<dim3(25, 4, kB), 256, 0, stream>>>(z, w2t, alphap, out, nullptr);
}

// Round 4
// 434.096 us; speedup vs baseline: 9.4929x; 1.0010x over previous
//
#include <hip/hip_runtime.h>
#include <hip/hip_bf16.h>
#include <cstddef>

// NLBasicBlock fused, round 4: 2-stage register-prefetch pipeline in the two
// latency-bound MFMA kernels (k_nl, k_colstat). R3's loads were serialized
// (VGPR=32) -> each iter ~8 dependent L2 round trips. Now next iteration's
// fragments are issued while current one computes.

constexpr int kB = 2, kC = 64, kH = 80, kW = 80, kN = kH * kW;
constexpr float kLOG2E = 1.4426950408889634f;
constexpr float kSHIFT = 28.853900817779268f;  // 20 * log2(e)

typedef __attribute__((ext_vector_type(8))) short short8;
typedef __attribute__((ext_vector_type(4))) float f32x4;

__device__ __forceinline__ int refl(int i, int n) {
  return i < 0 ? -i : (i >= n ? 2 * n - 2 - i : i);
}

__device__ __forceinline__ uint pkbf(float a, float b) {
  union { __hip_bfloat162 h; uint u; } x;
  x.h.x = __float2bfloat16(a);
  x.h.y = __float2bfloat16(b);
  return x.u;
}

#define FMA64(wrp, xv)                                   \
  {                                                      \
    _Pragma("unroll") for (int o_ = 0; o_ < 64; ++o_)    \
        acc[o_] += (wrp)[o_] * (xv);                     \
  }

// ---- weight prep
__global__ void k_prep(const float* __restrict__ w1, const float* __restrict__ w2,
                       const float* __restrict__ wg, const float* __restrict__ wth,
                       const float* __restrict__ wph, const float* __restrict__ wWm,
                       float* __restrict__ w1t, float* __restrict__ w2t,
                       float* __restrict__ wtht, float* __restrict__ wpht,
                       float* __restrict__ wgt, __hip_bfloat16* __restrict__ wWb) {
  int idx = blockIdx.x * 256 + threadIdx.x;
  if (idx < kC * kC * 9) {
    int o = idx / (kC * 9);
    int r = idx % (kC * 9);
    int ci = r / 9, tap = r % 9;
    int d = (ci * 9 + tap) * kC + o;
    w1t[d] = w1[idx];
    w2t[d] = w2[idx];
  }
  if (idx < kC * kC) {
    int o = idx / kC, c = idx % kC;
    int d = c * kC + o;
    wtht[d] = wth[idx];
    wpht[d] = wph[idx];
    wgt[d] = wg[idx];
    wWb[idx] = __float2bfloat16(wWm[idx]);
  }
}

// ---- 3x3 reflect conv (unchanged)
template <int MODE>
__global__ __launch_bounds__(256) void k_conv3x3(
    const float* __restrict__ src, const float* __restrict__ wt,
    const float* __restrict__ alphap, float* __restrict__ dst_raw,
    float* __restrict__ dst_pt) {
  const int tile = blockIdx.x;
  const int cog = blockIdx.y;
  const int b = blockIdx.z;
  const int ty0 = (tile / 5) * 16, tx0 = (tile % 5) * 16;
  const int tid = threadIdx.x;
  const int ty = tid / 16, tx = tid % 16;
  const float alpha = alphap[0];

  __shared__ float lds[32 * 18 * 18];
  float acc[16];
#pragma unroll
  for (int o = 0; o < 16; ++o) acc[o] = 0.f;

  for (int chunk = 0; chunk < 2; ++chunk) {
    const int ci0 = chunk * 32;
    __syncthreads();
    for (int idx = tid; idx < 32 * 324; idx += 256) {
      int cc = idx / 324;
      int r = idx % 324;
      int hh = r / 18, ww = r % 18;
      int gh = refl(ty0 - 1 + hh, kH);
      int gw = refl(tx0 - 1 + ww, kW);
      lds[idx] = src[(((size_t)b * kC + ci0 + cc) * kH + gh) * kW + gw];
    }
    __syncthreads();
    for (int cc = 0; cc < 32; ++cc) {
#pragma unroll
      for (int tap = 0; tap < 9; ++tap) {
        const int dh = tap / 3, dw = tap % 3;
        const float xv = lds[cc * 324 + (ty + dh) * 18 + (tx + dw)];
        const float* wr = wt + ((size_t)(ci0 + cc) * 9 + tap) * kC + cog * 16;
#pragma unroll
        for (int o = 0; o < 16; ++o) acc[o] += wr[o] * xv;
      }
    }
  }

  const int n = (ty0 + ty) * kW + (tx0 + tx);
#pragma unroll
  for (int o = 0; o < 16; ++o) {
    const int co = cog * 16 + o;
    const float v = acc[o];
    const float p = v >= 0.f ? v : alpha * v;
    if (MODE == 0) {
      dst_raw[((size_t)b * kC + co) * kN + n] = v;
      dst_pt[((size_t)b * kN + n) * kC + co] = p;
    } else {
      dst_raw[((size_t)b * kC + co) * kN + n] = p;
    }
  }
}

// ---- three 1x1 convs -> bf16 pixel-major
__global__ __launch_bounds__(64) void k_pw3(const float* __restrict__ pT,
                                            const float* __restrict__ wt3,
                                            __hip_bfloat16* __restrict__ outb) {
  const int m = blockIdx.z, b = blockIdx.y;
  const int n = blockIdx.x * 64 + threadIdx.x;
  const float* wt = wt3 + (size_t)m * kC * kC;
  const float4* p4 = (const float4*)(pT + ((size_t)b * kN + n) * kC);
  float acc[64];
#pragma unroll
  for (int o = 0; o < 64; ++o) acc[o] = 0.f;
#pragma unroll
  for (int cq = 0; cq < 16; ++cq) {
    const float4 t = p4[cq];
    const float* wr = wt + cq * 4 * 64;
    FMA64(wr, t.x);
    FMA64(wr + 64, t.y);
    FMA64(wr + 128, t.z);
    FMA64(wr + 192, t.w);
  }
  uint* d32 = (uint*)(outb + (((size_t)m * kB + b) * kN + n) * kC);
#pragma unroll
  for (int q = 0; q < 32; ++q) d32[q] = pkbf(acc[2 * q], acc[2 * q + 1]);
}

// ---- column sums, 2-stage pipelined.
__global__ __launch_bounds__(256, 3) void k_colstat(
    const __hip_bfloat16* __restrict__ th, const __hip_bfloat16* __restrict__ ph,
    float* __restrict__ partial) {
  const int b = blockIdx.z, ic = blockIdx.y;
  const int lane = threadIdx.x & 63, w = threadIdx.x >> 6;
  const int il = lane & 15, hi = lane >> 4;
  const int j0 = blockIdx.x * 64 + w * 16;

  const short8 af0 = *(const short8*)&ph[((size_t)b * kN + j0 + il) * kC + hi * 8];
  const short8 af1 = *(const short8*)&ph[((size_t)b * kN + j0 + il) * kC + 32 + hi * 8];
  const __hip_bfloat16* thB = th + (size_t)b * kN * kC;

  float cs[4] = {0.f, 0.f, 0.f, 0.f};
  short8 b0aA, b1aA, b0bA, b1bA, b0aB, b1aB, b0bB, b1bB;

#define LOADI(S, I)                                                           \
  b0a##S = *(const short8*)&thB[(size_t)((I) + il) * kC + hi * 8];            \
  b1a##S = *(const short8*)&thB[(size_t)((I) + il) * kC + 32 + hi * 8];       \
  b0b##S = *(const short8*)&thB[(size_t)((I) + 16 + il) * kC + hi * 8];       \
  b1b##S = *(const short8*)&thB[(size_t)((I) + 16 + il) * kC + 32 + hi * 8];

#define COMPI(S)                                                              \
  {                                                                           \
    f32x4 sa = {0.f, 0.f, 0.f, 0.f};                                          \
    f32x4 sb = {0.f, 0.f, 0.f, 0.f};                                          \
    sa = __builtin_amdgcn_mfma_f32_16x16x32_bf16(af0, b0a##S, sa, 0, 0, 0);   \
    sa = __builtin_amdgcn_mfma_f32_16x16x32_bf16(af1, b1a##S, sa, 0, 0, 0);   \
    sb = __builtin_amdgcn_mfma_f32_16x16x32_bf16(af0, b0b##S, sb, 0, 0, 0);   \
    sb = __builtin_amdgcn_mfma_f32_16x16x32_bf16(af1, b1b##S, sb, 0, 0, 0);   \
    _Pragma("unroll") for (int r = 0; r < 4; ++r)                             \
        cs[r] += exp2f(fmaf(sa[r], kLOG2E, -kSHIFT)) +                        \
                 exp2f(fmaf(sb[r], kLOG2E, -kSHIFT));                         \
  }

  int i = ic * (kN / 4);
  const int ilast = i + (kN / 4) - 64;
  LOADI(A, i)
  for (; i < ilast; i += 64) {
    LOADI(B, i + 32)
    COMPI(A)
    LOADI(A, i + 64)
    COMPI(B)
  }
  LOADI(B, i + 32)
  COMPI(A)
  COMPI(B)
#undef LOADI
#undef COMPI

#pragma unroll
  for (int r = 0; r < 4; ++r) {
    cs[r] += __shfl_xor(cs[r], 1);
    cs[r] += __shfl_xor(cs[r], 2);
    cs[r] += __shfl_xor(cs[r], 4);
    cs[r] += __shfl_xor(cs[r], 8);
  }
  if (il == 0) {
    float* p = partial + ((size_t)(b * 4 + ic)) * kN + j0 + hi * 4;
#pragma unroll
    for (int r = 0; r < 4; ++r) p[r] = cs[r];
  }
}

// ---- gT[b][c][j] = bf16( g[b][j][c] * 1/colsum[b][j] )
__global__ __launch_bounds__(256) void k_gscale(
    const __hip_bfloat16* __restrict__ gb, const float* __restrict__ partial,
    __hip_bfloat16* __restrict__ gT) {
  const int b = blockIdx.y;
  const int j0 = blockIdx.x * 64;
  const int t = threadIdx.x;
  __shared__ ushort tile[64][66];
  __shared__ float rsv[64];
  if (t < 64) {
    const int j = j0 + t;
    float cs = partial[(size_t)(b * 4 + 0) * kN + j] +
               partial[(size_t)(b * 4 + 1) * kN + j] +
               partial[(size_t)(b * 4 + 2) * kN + j] +
               partial[(size_t)(b * 4 + 3) * kN + j];
    rsv[t] = 1.0f / cs;
  }
  {
    const int jl = t >> 2, cseg = (t & 3) * 16;
    const ushort* src = (const ushort*)&gb[((size_t)b * kN + j0 + jl) * kC + cseg];
    union { short8 v; ushort u[8]; } u0, u1;
    u0.v = *(const short8*)src;
    u1.v = *(const short8*)(src + 8);
#pragma unroll
    for (int k = 0; k < 8; ++k) {
      tile[jl][cseg + k] = u0.u[k];
      tile[jl][cseg + 8 + k] = u1.u[k];
    }
  }
  __syncthreads();
  const int c = t >> 2, jseg = (t & 3) * 16;
  union { short8 v; ushort u[8]; } o0, o1;
#pragma unroll
  for (int k = 0; k < 16; ++k) {
    const int j = jseg + k;
    const float gv = __uint_as_float((uint)tile[j][c] << 16);
    union { __hip_bfloat16 h; ushort us; } cv;
    cv.h = __float2bfloat16(gv * rsv[j]);
    if (k < 8) o0.u[k] = cv.us; else o1.u[k - 8] = cv.us;
  }
  short8* dst = (short8*)&gT[((size_t)b * kC + c) * kN + j0 + jseg];
  dst[0] = o0.v;
  dst[1] = o1.v;
}

// ---- fused pass B + W_y + residuals, 2-stage pipelined.
__global__ __launch_bounds__(256, 3) void k_nl(
    const __hip_bfloat16* __restrict__ th, const __hip_bfloat16* __restrict__ ph,
    const __hip_bfloat16* __restrict__ gT, const __hip_bfloat16* __restrict__ wWb,
    const float* __restrict__ x1, const float* __restrict__ alphap,
    float* __restrict__ z) {
  const int b = blockIdx.y;
  const int lane = threadIdx.x & 63, w = threadIdx.x >> 6;
  const int il = lane & 15, hi = lane >> 4;
  const int i0 = blockIdx.x * 16;
  const int jbase = ((il >> 2) << 3) + (il & 3);  // sigma(row=il)

  __shared__ float red[4][16][64];
  __shared__ ushort ytile[16 * 72];

  const short8 tb0 = *(const short8*)&th[((size_t)b * kN + i0 + il) * kC + hi * 8];
  const short8 tb1 = *(const short8*)&th[((size_t)b * kN + i0 + il) * kC + 32 + hi * 8];

  f32x4 accy0 = {0.f, 0.f, 0.f, 0.f};
  f32x4 accy1 = {0.f, 0.f, 0.f, 0.f};
  f32x4 accy2 = {0.f, 0.f, 0.f, 0.f};
  f32x4 accy3 = {0.f, 0.f, 0.f, 0.f};

  const __hip_bfloat16* phB = ph + (size_t)b * kN * kC;
  const __hip_bfloat16* gTB = gT + (size_t)b * kC * kN;

  short8 pa00A, pa01A, pa10A, pa11A, ga0A, ga1A, ga2A, ga3A;
  short8 pa00B, pa01B, pa10B, pa11B, ga0B, ga1B, ga2B, ga3B;

#define LOADJ(S, JG)                                                          \
  {                                                                           \
    const size_t r0_ = (size_t)((JG) + jbase) * kC;                           \
    const size_t r1_ = (size_t)((JG) + jbase + 4) * kC;                       \
    pa00##S = *(const short8*)&phB[r0_ + hi * 8];                             \
    pa01##S = *(const short8*)&phB[r0_ + 32 + hi * 8];                        \
    pa10##S = *(const short8*)&phB[r1_ + hi * 8];                             \
    pa11##S = *(const short8*)&phB[r1_ + 32 + hi * 8];                        \
    ga0##S = *(const short8*)&gTB[(size_t)il * kN + (JG) + hi * 8];           \
    ga1##S = *(const short8*)&gTB[(size_t)(16 + il) * kN + (JG) + hi * 8];    \
    ga2##S = *(const short8*)&gTB[(size_t)(32 + il) * kN + (JG) + hi * 8];    \
    ga3##S = *(const short8*)&gTB[(size_t)(48 + il) * kN + (JG) + hi * 8];    \
  }

#define COMPJ(S)                                                              \
  {                                                                           \
    f32x4 s0 = {0.f, 0.f, 0.f, 0.f};                                          \
    f32x4 s1 = {0.f, 0.f, 0.f, 0.f};                                          \
    s0 = __builtin_amdgcn_mfma_f32_16x16x32_bf16(pa00##S, tb0, s0, 0, 0, 0);  \
    s0 = __builtin_amdgcn_mfma_f32_16x16x32_bf16(pa01##S, tb1, s0, 0, 0, 0);  \
    s1 = __builtin_amdgcn_mfma_f32_16x16x32_bf16(pa10##S, tb0, s1, 0, 0, 0);  \
    s1 = __builtin_amdgcn_mfma_f32_16x16x32_bf16(pa11##S, tb1, s1, 0, 0, 0);  \
    const float e0 = exp2f(fmaf(s0[0], kLOG2E, -kSHIFT));                     \
    const float e1 = exp2f(fmaf(s0[1], kLOG2E, -kSHIFT));                     \
    const float e2 = exp2f(fmaf(s0[2], kLOG2E, -kSHIFT));                     \
    const float e3 = exp2f(fmaf(s0[3], kLOG2E, -kSHIFT));                     \
    const float e4 = exp2f(fmaf(s1[0], kLOG2E, -kSHIFT));                     \
    const float e5 = exp2f(fmaf(s1[1], kLOG2E, -kSHIFT));                     \
    const float e6 = exp2f(fmaf(s1[2], kLOG2E, -kSHIFT));                     \
    const float e7 = exp2f(fmaf(s1[3], kLOG2E, -kSHIFT));                     \
    short8 pb;                                                                \
    uint* pw_ = (uint*)&pb;                                                   \
    pw_[0] = pkbf(e0, e1);                                                    \
    pw_[1] = pkbf(e2, e3);                                                    \
    pw_[2] = pkbf(e4, e5);                                                    \
    pw_[3] = pkbf(e6, e7);                                                    \
    accy0 = __builtin_amdgcn_mfma_f32_16x16x32_bf16(ga0##S, pb, accy0, 0, 0, 0); \
    accy1 = __builtin_amdgcn_mfma_f32_16x16x32_bf16(ga1##S, pb, accy1, 0, 0, 0); \
    accy2 = __builtin_amdgcn_mfma_f32_16x16x32_bf16(ga2##S, pb, accy2, 0, 0, 0); \
    accy3 = __builtin_amdgcn_mfma_f32_16x16x32_bf16(ga3##S, pb, accy3, 0, 0, 0); \
  }

  int jg = w * (kN / 4);
  const int jlast = jg + (kN / 4) - 64;
  LOADJ(A, jg)
  for (; jg < jlast; jg += 64) {
    LOADJ(B, jg + 32)
    COMPJ(A)
    LOADJ(A, jg + 64)
    COMPJ(B)
  }
  LOADJ(B, jg + 32)
  COMPJ(A)
  COMPJ(B)
#undef LOADJ
#undef COMPJ

  {
    const f32x4* accp[4] = {&accy0, &accy1, &accy2, &accy3};
#pragma unroll
    for (int ct = 0; ct < 4; ++ct)
#pragma unroll
      for (int r = 0; r < 4; ++r) red[w][ct * 4 + r][lane] = (*accp[ct])[r];
  }
  __syncthreads();
  if (w == 0) {
#pragma unroll
    for (int k = 0; k < 16; k += 2) {
      const float va = red[0][k][lane] + red[1][k][lane] + red[2][k][lane] +
                       red[3][k][lane];
      const float vb = red[0][k + 1][lane] + red[1][k + 1][lane] +
                       red[2][k + 1][lane] + red[3][k + 1][lane];
      const int c0 = ((k >> 2) << 4) + hi * 4 + (k & 3);
      *(uint*)&ytile[il * 72 + c0] = pkbf(va, vb);
    }
  }
  __syncthreads();

  const short8 af0 = *(const short8*)&wWb[(size_t)(w * 16 + il) * kC + hi * 8];
  const short8 af1 = *(const short8*)&wWb[(size_t)(w * 16 + il) * kC + 32 + hi * 8];
  const short8 by0 = *(const short8*)&ytile[il * 72 + hi * 8];
  const short8 by1 = *(const short8*)&ytile[il * 72 + 32 + hi * 8];
  f32x4 o4 = {0.f, 0.f, 0.f, 0.f};
  o4 = __builtin_amdgcn_mfma_f32_16x16x32_bf16(af0, by0, o4, 0, 0, 0);
  o4 = __builtin_amdgcn_mfma_f32_16x16x32_bf16(af1, by1, o4, 0, 0, 0);
  const float alpha = alphap[0];
#pragma unroll
  for (int r = 0; r < 4; ++r) {
    const int o = w * 16 + hi * 4 + r;
    const size_t idx = ((size_t)b * kC + o) * kN + i0 + il;
    const float xv = x1[idx];
    const float p = xv >= 0.f ? xv : alpha * xv;
    z[idx] = o4[r] + p + xv;
  }
}

extern "C" void kernel_launch(void* const* d_in, const int* in_sizes, int n_in,
                              void* d_out, int out_size, void* d_ws, size_t ws_size,
                              hipStream_t stream) {
  const float* x      = (const float*)d_in[0];
  const float* w1     = (const float*)d_in[1];
  const float* w2     = (const float*)d_in[2];
  const float* wg     = (const float*)d_in[3];
  const float* wth    = (const float*)d_in[4];
  const float* wph    = (const float*)d_in[5];
  const float* wWm    = (const float*)d_in[6];
  const float* alphap = (const float*)d_in[7];
  float* out = (float*)d_out;

  const size_t SZ = (size_t)kB * kC * kN;  // 819200 elements
  float* x1 = (float*)d_ws;                          // [B][C][N] f32
  float* pT = x1 + SZ;                               // [B][N][C] f32; reused as z
  __hip_bfloat16* thb = (__hip_bfloat16*)(pT + SZ);  // [B][N][C] bf16
  __hip_bfloat16* phb = thb + SZ;
  __hip_bfloat16* gb  = phb + SZ;
  __hip_bfloat16* gT  = gb + SZ;                     // [B][C][N] bf16 (rs-scaled)
  float* partial = (float*)(gT + SZ);                // [B][4][N] f32
  float* w1t = partial + (size_t)kB * 4 * kN;
  float* w2t = w1t + kC * kC * 9;
  float* wt3 = w2t + kC * kC * 9;
  __hip_bfloat16* wWb = (__hip_bfloat16*)(wt3 + 3 * kC * kC);
  float* z = pT;  // pT dead after k_pw3

  k_prep<<<144, 256, 0, stream>>>(w1, w2, wg, wth, wph, wWm, w1t, w2t,
                                  wt3, wt3 + kC * kC, wt3 + 2 * kC * kC, wWb);
  k_conv3x3<0><<<dim3(25, 4, kB), 256, 0, stream>>>(x, w1t, alphap, x1, pT);
  k_pw3<<<dim3(kN / 64, kB, 3), 64, 0, stream>>>(pT, wt3, thb);
  k_colstat<<<dim3(kN / 64, 4, kB), 256, 0, stream>>>(thb, phb, partial);
  k_gscale<<<dim3(kN / 64, kB), 256, 0, stream>>>(gb, partial, gT);
  k_nl<<<dim3(kN / 16, kB), 256, 0, stream>>>(thb, phb, gT, wWb, x1, alphap, z);
  k_conv3x3<1><<<dim3(25, 4, kB), 256, 0, stream>>>(z, w2t, alphap, out, nullptr);
}